// Round 8
// baseline (925.702 us; speedup 1.0000x reference)
//
#include <hip/hip_runtime.h>
#include <stdint.h>

#define KOFF 27
#define CIN 64
#define COUT 128
#define EPS 1e-5f

using frag_ab = __attribute__((ext_vector_type(8))) short;
using frag_cd = __attribute__((ext_vector_type(4))) float;

__device__ __forceinline__ float bf2f(unsigned short u) {
  union { unsigned int i; float f; } x; x.i = ((unsigned int)u) << 16; return x.f;
}
__device__ __forceinline__ unsigned short f2bf(float f) {
  union { float f; unsigned int i; } x; x.f = f;
  unsigned int u = x.i;
  u += 0x7fffu + ((u >> 16) & 1u);   // round-to-nearest-even
  return (unsigned short)(u >> 16);
}

// async global->LDS, 16 B per lane; LDS dest = wave-uniform base + lane*16
__device__ __forceinline__ void gld16(const void* gptr, void* lptr) {
  __builtin_amdgcn_global_load_lds(
      (const __attribute__((address_space(1))) unsigned int*)gptr,
      (__attribute__((address_space(3))) unsigned int*)lptr, 16, 0, 0);
}

// ---------------------------------------------------------------------------
// BARRIER-FREE gather-GEMM: Y[row] = sum_k X[nbr[k][row]] @ W[k].
// Wave-private decomposition: each wave owns M=32 rows x N=128 cols
// (acc 2x8 tiles, 64 AGPR). A: each wave global_load_lds's ITS OWN rows into
// ITS OWN LDS stripe -> no inter-wave LDS sharing -> ZERO s_barrier in the
// K-loop; waves free-run (AITER-style). 4-stage LDS ring (4 x 2 KB/wave,
// 32 KB/block). B (L2-hot weights): 8 reg frags, double-buffered 1 iter
// ahead from slab layout [ko*NC+kc][q][co][8].
// Per-iter issue order: [wait vmcnt(W)] [ds_read A] [loadB(t+1)] [idx?]
// [stageA(t+3)] [MFMA]. Queue algebra: wait-through-B(t) leaves the 2 newest
// A-stages (+idx pair on post-idx slots) in flight -> A gets 2 iterations of
// latency budget, B gets 1. W = 4 on slot (2 % NC), else 2.
// Masked rows (idx<0) read a 256 B zero page -> zero acc -> fused BN stats
// stay exact. koff >= 2 assumed (identity/skip path uses convskip_kernel).
// ---------------------------------------------------------------------------
template <int CI, bool GATHER, bool OF32>
__global__ __launch_bounds__(256, 2) void conv_kernel(
    const unsigned short* __restrict__ X, const int* __restrict__ nbr,
    const unsigned short* __restrict__ Wt, void* __restrict__ Yv,
    const unsigned short* __restrict__ zpage, float* __restrict__ sums,
    int n, int koff) {
  constexpr int NC = CI / 32;       // 32-ch chunks per offset (2 or 4)
  constexpr int LOG = (NC == 4) ? 2 : 1;
  __shared__ unsigned short Alds[4][4][1024];  // [stage][wave][32 rows * 32ch]

  const int tid = threadIdx.x;
  const int lane = tid & 63;
  const int wave = tid >> 6;
  const int row0 = blockIdx.x * 128;
  const int wstripe = wave * 32;
  const int m = lane & 15;
  const int q = lane >> 4;
  const int srow = lane >> 2;  // 0..15 (glds: 4 lanes x 16 B per row)
  const int sl = lane & 3;

  frag_cd acc[2][8];
#pragma unroll
  for (int i = 0; i < 2; ++i)
#pragma unroll
    for (int j = 0; j < 8; ++j) acc[i][j] = (frag_cd){0.f, 0.f, 0.f, 0.f};

  frag_ab bA[8], bB[8];
  int idxc[2], idxn[2];

  auto load_idx = [&](int ko, int (&dst)[2]) {
#pragma unroll
    for (int i = 0; i < 2; ++i) {
      const int grow = row0 + wstripe + 16 * i + srow;
      int v = -1;
      if (grow < n) v = GATHER ? nbr[(size_t)ko * n + grow] : grow;
      dst[i] = v;
    }
  };
  auto stageA = [&](int st, int ko, int kc, const int (&idx)[2]) {
#pragma unroll
    for (int i = 0; i < 2; ++i) {
      const int row = 16 * i + srow;           // local row in stripe
      const int g = sl ^ ((row >> 1) & 3);     // fetch-side swizzle
      const unsigned short* ga =
          (idx[i] >= 0) ? X + (size_t)idx[i] * CI + kc * 32 + g * 8 : zpage;
      gld16(ga, &Alds[st][wave][i * 512]);
    }
  };
  auto loadB = [&](frag_ab (&b)[8], int ko, int kc) {
    const unsigned short* base =
        Wt + (size_t)(ko * NC + kc) * 4096 + q * 1024 + m * 8;
#pragma unroll
    for (int j = 0; j < 8; ++j)
      b[j] = *(const frag_ab*)(base + j * 128);
  };
  auto do_mfma = [&](int st, frag_ab (&b)[8]) {
    frag_ab a[2];
#pragma unroll
    for (int i = 0; i < 2; ++i) {
      const int row = 16 * i + m;
      a[i] = *(const frag_ab*)(&Alds[st][wave][row * 32 + (q ^ ((row >> 1) & 3)) * 8]);
    }
#pragma unroll
    for (int i = 0; i < 2; ++i)
#pragma unroll
      for (int j = 0; j < 8; ++j)
        acc[i][j] = __builtin_amdgcn_mfma_f32_16x16x32_bf16(a[i], b[j],
                                                            acc[i][j], 0, 0, 0);
  };

  const int T = koff * NC;

  // ---- prologue: B(0) first (so wait-through-B(0) preserves A flight),
  //      then A stages 0,1,2 ----
  load_idx(0, idxc);
  load_idx(1, idxn);
  loadB(bA, 0, 0);
  stageA(0, 0, 0, idxc);
  stageA(1, 0, 1, idxc);
  if (NC == 2) {
    stageA(2, 1, 0, idxn);
    idxc[0] = idxn[0]; idxc[1] = idxn[1];   // staging ko is now 1
    if (koff > 2) load_idx(2, idxn);
  } else {
    stageA(2, 0, 2, idxc);
  }

  auto body = [&](int t, int W, frag_ab (&bcur)[8], frag_ab (&bnxt)[8]) {
    if (W == 4) asm volatile("s_waitcnt vmcnt(4)" ::: "memory");
    else        asm volatile("s_waitcnt vmcnt(2)" ::: "memory");
    const int u = t + 1;
    loadB(bnxt, u >> LOG, u & (NC - 1));
    if ((t & (NC - 1)) == 1) {             // staging crosses into new ko
      const int kos = (t + 3) >> LOG;
      idxc[0] = idxn[0]; idxc[1] = idxn[1];
      if (GATHER && kos + 1 < koff) load_idx(kos + 1, idxn);
    }
    const int s = t + 3;
    stageA(s & 3, s >> LOG, s & (NC - 1), idxc);
    do_mfma(t & 3, bcur);
  };
  auto tail = [&](int t, frag_ab (&bcur)[8], frag_ab (&bnxt)[8]) {
    asm volatile("s_waitcnt vmcnt(0)" ::: "memory");
    const int u = t + 1;
    if (u < T) loadB(bnxt, u >> LOG, u & (NC - 1));
    const int s = t + 3;
    if (s < T) stageA(s & 3, s >> LOG, s & (NC - 1), idxc);
    do_mfma(t & 3, bcur);
  };

  // main: groups of NC; last group start ts satisfies ts+NC-1 <= T-4
  const int Tm = ((T - NC - 3) / NC) * NC + NC;  // exclusive main end
  int t = 0;
  for (; t < Tm; t += NC) {
    if (NC == 4) {
      body(t + 0, 2, bA, bB);
      body(t + 1, 2, bB, bA);
      body(t + 2, 4, bA, bB);
      body(t + 3, 2, bB, bA);
    } else {
      body(t + 0, 4, bA, bB);
      body(t + 1, 2, bB, bA);
    }
  }
  // remainder: exactly 4 iterations (T ≡ 0 mod NC, Tm = T-4), Tm even
  tail(t + 0, bA, bB);
  tail(t + 1, bB, bA);
  tail(t + 2, bA, bB);
  tail(t + 3, bB, bA);

  // ---- fused BN stats: per-channel sum/sumsq over this wave's 32 rows ----
#pragma unroll
  for (int j = 0; j < 8; ++j) {
    float s = 0.f, qq = 0.f;
#pragma unroll
    for (int i = 0; i < 2; ++i)
#pragma unroll
      for (int r = 0; r < 4; ++r) {
        float v = acc[i][j][r];
        s += v; qq += v * v;
      }
    s += __shfl_xor(s, 16); s += __shfl_xor(s, 32);
    qq += __shfl_xor(qq, 16); qq += __shfl_xor(qq, 32);
    if (lane < 16) {
      const int col = 16 * j + lane;
      atomicAdd(&sums[col], s);
      atomicAdd(&sums[COUT + col], qq);
    }
  }

  // ---- epilogue: C/D layout col=lane&15, row=(lane>>4)*4+reg ----
#pragma unroll
  for (int i = 0; i < 2; ++i) {
#pragma unroll
    for (int r = 0; r < 4; ++r) {
      const int grow = row0 + wstripe + 16 * i + q * 4 + r;
      if (grow < n) {
#pragma unroll
        for (int j = 0; j < 8; ++j) {
          const int gcol = 16 * j + m;
          if (OF32)
            ((float*)Yv)[(size_t)grow * COUT + gcol] = acc[i][j][r];
          else
            ((unsigned short*)Yv)[(size_t)grow * COUT + gcol] = f2bf(acc[i][j][r]);
        }
      }
    }
  }
}

// ---------------------------------------------------------------------------
// Fused: fp32->bf16 convert of feats (writes featsb) + skip GEMM feats@Wd
// (B transposed from fp32 Wd on the fly) + fused skip BN stats.
// ---------------------------------------------------------------------------
__global__ __launch_bounds__(256, 2) void convskip_kernel(
    const float* __restrict__ feats, const float* __restrict__ Wd,
    unsigned short* __restrict__ featsb, unsigned short* __restrict__ sX,
    float* __restrict__ sums, int n) {
  __shared__ unsigned short Alds[2][128 * 32];
  const int tid = threadIdx.x;
  const int lane = tid & 63;
  const int wave = tid >> 6;
  const int row0 = blockIdx.x * 128;
  const int wrow = (wave >> 1) * 64;
  const int wcol = (wave & 1) * 64;
  const int m = lane & 15;
  const int q = lane >> 4;

#pragma unroll
  for (int c = 0; c < 4; ++c) {
    int u = c * 256 + tid;
    int kc = u >> 9;
    int v = u & 511;
    int row = v >> 2;
    int s = v & 3;
    int g = s ^ ((row >> 1) & 3);
    int grow = row0 + row;
    uint4 out = make_uint4(0u, 0u, 0u, 0u);
    if (grow < n) {
      const float* p = feats + (size_t)grow * 64 + kc * 32 + g * 8;
      float4 lo = *(const float4*)p;
      float4 hi = *(const float4*)(p + 4);
      out.x = (unsigned)f2bf(lo.x) | ((unsigned)f2bf(lo.y) << 16);
      out.y = (unsigned)f2bf(lo.z) | ((unsigned)f2bf(lo.w) << 16);
      out.z = (unsigned)f2bf(hi.x) | ((unsigned)f2bf(hi.y) << 16);
      out.w = (unsigned)f2bf(hi.z) | ((unsigned)f2bf(hi.w) << 16);
      *(uint4*)(featsb + (size_t)grow * 64 + kc * 32 + g * 8) = out;
    }
    *(uint4*)(&Alds[kc][row * 32 + s * 8]) = out;
  }
  __syncthreads();

  frag_cd acc[4][4];
#pragma unroll
  for (int i = 0; i < 4; ++i)
#pragma unroll
    for (int j = 0; j < 4; ++j) acc[i][j] = (frag_cd){0.f, 0.f, 0.f, 0.f};

#pragma unroll
  for (int kc = 0; kc < 2; ++kc) {
    frag_ab b[4];
#pragma unroll
    for (int j = 0; j < 4; ++j) {
      const int co = wcol + 16 * j + m;
#pragma unroll
      for (int e = 0; e < 8; ++e)
        b[j][e] = (short)f2bf(Wd[(size_t)(kc * 32 + q * 8 + e) * 128 + co]);
    }
    frag_ab a[4];
#pragma unroll
    for (int i = 0; i < 4; ++i) {
      const int row = wrow + 16 * i + m;
      a[i] = *(const frag_ab*)(&Alds[kc][row * 32 + (q ^ ((row >> 1) & 3)) * 8]);
    }
#pragma unroll
    for (int i = 0; i < 4; ++i)
#pragma unroll
      for (int j = 0; j < 4; ++j)
        acc[i][j] = __builtin_amdgcn_mfma_f32_16x16x32_bf16(a[i], b[j],
                                                            acc[i][j], 0, 0, 0);
  }

#pragma unroll
  for (int j = 0; j < 4; ++j) {
    float s = 0.f, qq = 0.f;
#pragma unroll
    for (int i = 0; i < 4; ++i)
#pragma unroll
      for (int r = 0; r < 4; ++r) {
        float v = acc[i][j][r];
        s += v; qq += v * v;
      }
    s += __shfl_xor(s, 16); s += __shfl_xor(s, 32);
    qq += __shfl_xor(qq, 16); qq += __shfl_xor(qq, 32);
    if (lane < 16) {
      const int col = wcol + 16 * j + lane;
      atomicAdd(&sums[col], s);
      atomicAdd(&sums[COUT + col], qq);
    }
  }

#pragma unroll
  for (int i = 0; i < 4; ++i) {
#pragma unroll
    for (int r = 0; r < 4; ++r) {
      const int grow = row0 + wrow + 16 * i + q * 4 + r;
      if (grow < n) {
#pragma unroll
        for (int j = 0; j < 4; ++j)
          sX[(size_t)grow * COUT + wcol + 16 * j + m] = f2bf(acc[i][j][r]);
      }
    }
  }
}

// ---------------------------------------------------------------------------
// prep: zero sums (768 floats) + zpage (64 floats) + Wt1/Wt2 slab transposes.
// slab layout: dst[((ko*nc+kc)*4+q)*1024 + co*8 + e] = bf16(src[ko][kc*32+q*8+e][co])
// ---------------------------------------------------------------------------
__global__ void prep_kernel(const float* __restrict__ W1,
                            const float* __restrict__ W2,
                            unsigned short* __restrict__ Wt1,
                            unsigned short* __restrict__ Wt2,
                            float* __restrict__ zbase,
                            float* __restrict__ zpage) {
  const int NZ = 768 + 64;
  const int NW1 = KOFF * CIN * 128;    // 221184
  const int NW2 = KOFF * COUT * 128;   // 442368
  int gid = blockIdx.x * 256 + threadIdx.x;
  if (gid < NZ) {
    if (gid < 768) zbase[gid] = 0.f; else zpage[gid - 768] = 0.f;
    return;
  }
  gid -= NZ;
  const float* src;
  unsigned short* dst;
  int ci;
  if (gid < NW1) { src = W1; dst = Wt1; ci = CIN; }
  else if (gid < NW1 + NW2) { gid -= NW1; src = W2; dst = Wt2; ci = COUT; }
  else return;
  int e = gid & 7;
  int co = (gid >> 3) & 127;
  int qq = (gid >> 10) & 3;
  int slab = gid >> 12;
  int nc = ci >> 5;
  int ko = slab / nc;
  int kc = slab - ko * nc;
  int cin = kc * 32 + qq * 8 + e;
  dst[gid] = f2bf(src[((size_t)ko * ci + cin) * 128 + co]);
}

// in-place bf16 x = relu(x*scale + shift); finalize fused (per-block LDS)
__global__ void norm_relu_kernel(unsigned short* __restrict__ x,
                                 const float* __restrict__ sums,
                                 const float* __restrict__ gamma,
                                 const float* __restrict__ beta,
                                 int n, int total8) {
  __shared__ float sc[COUT], sh[COUT];
  const int tid = threadIdx.x;
  if (tid < COUT) {
    float inv_n = 1.f / (float)n;
    float mean = sums[tid] * inv_n;
    float var = sums[COUT + tid] * inv_n - mean * mean;
    float s = gamma[tid] * rsqrtf(var + EPS);
    sc[tid] = s;
    sh[tid] = beta[tid] - mean * s;
  }
  __syncthreads();
  int gid = blockIdx.x * 256 + tid;
  if (gid >= total8) return;
  size_t i = (size_t)gid * 8;
  int c0 = (int)(i & 127);
  uint4 v = *(const uint4*)(x + i);
  unsigned int w[4] = {v.x, v.y, v.z, v.w};
  unsigned int wo[4];
#pragma unroll
  for (int e = 0; e < 4; ++e) {
    int c = c0 + 2 * e;
    float f0 = bf2f((unsigned short)(w[e] & 0xffffu));
    float f1 = bf2f((unsigned short)(w[e] >> 16));
    f0 = fmaxf(f0 * sc[c] + sh[c], 0.f);
    f1 = fmaxf(f1 * sc[c + 1] + sh[c + 1], 0.f);
    wo[e] = (unsigned int)f2bf(f0) | ((unsigned int)f2bf(f1) << 16);
  }
  *(uint4*)(x + i) = make_uint4(wo[0], wo[1], wo[2], wo[3]);
}

// out(fp32, in-place on h2) = relu(bn2(h2) + bnd(s)); finalize fused
__global__ void final_kernel(float* __restrict__ h2,
                             const unsigned short* __restrict__ s,
                             const float* __restrict__ sums2,
                             const float* __restrict__ sumsd,
                             const float* __restrict__ g2,
                             const float* __restrict__ b2,
                             const float* __restrict__ gd,
                             const float* __restrict__ bd,
                             int n, int total4) {
  __shared__ float sc2[COUT], sh2[COUT], scd[COUT], shd[COUT];
  const int tid = threadIdx.x;
  if (tid < COUT) {
    float inv_n = 1.f / (float)n;
    float mean = sums2[tid] * inv_n;
    float var = sums2[COUT + tid] * inv_n - mean * mean;
    float sa = g2[tid] * rsqrtf(var + EPS);
    sc2[tid] = sa;
    sh2[tid] = b2[tid] - mean * sa;
    mean = sumsd[tid] * inv_n;
    var = sumsd[COUT + tid] * inv_n - mean * mean;
    float sb = gd[tid] * rsqrtf(var + EPS);
    scd[tid] = sb;
    shd[tid] = bd[tid] - mean * sb;
  }
  __syncthreads();
  int gid = blockIdx.x * 256 + tid;
  if (gid >= total4) return;
  size_t i = (size_t)gid * 4;
  int c = (int)(i & 127);
  float4 a = *(const float4*)(h2 + i);
  uint2 sv = *(const uint2*)(s + i);
  float b0 = bf2f((unsigned short)(sv.x & 0xffffu));
  float b1 = bf2f((unsigned short)(sv.x >> 16));
  float b2f = bf2f((unsigned short)(sv.y & 0xffffu));
  float b3 = bf2f((unsigned short)(sv.y >> 16));
  float4 o;
  o.x = fmaxf(a.x * sc2[c] + sh2[c] + b0 * scd[c] + shd[c], 0.f);
  o.y = fmaxf(a.y * sc2[c + 1] + sh2[c + 1] + b1 * scd[c + 1] + shd[c + 1], 0.f);
  o.z = fmaxf(a.z * sc2[c + 2] + sh2[c + 2] + b2f * scd[c + 2] + shd[c + 2], 0.f);
  o.w = fmaxf(a.w * sc2[c + 3] + sh2[c + 3] + b3 * scd[c + 3] + shd[c + 3], 0.f);
  *(float4*)(h2 + i) = o;
}

extern "C" void kernel_launch(void* const* d_in, const int* in_sizes, int n_in,
                              void* d_out, int out_size, void* d_ws,
                              size_t ws_size, hipStream_t stream) {
  (void)n_in; (void)out_size; (void)ws_size;
  const float* feats = (const float*)d_in[0];
  const int* nbr1 = (const int*)d_in[1];
  const int* nbr2 = (const int*)d_in[2];
  const float* W1 = (const float*)d_in[3];
  const float* W2 = (const float*)d_in[4];
  const float* Wd = (const float*)d_in[5];
  const float* g1 = (const float*)d_in[6];
  const float* b1 = (const float*)d_in[7];
  const float* g2 = (const float*)d_in[8];
  const float* b2 = (const float*)d_in[9];
  const float* gd = (const float*)d_in[10];
  const float* bd = (const float*)d_in[11];

  const int n = in_sizes[0] / CIN;  // 200000

  // ws layout (known-good footprint):
  //   Wt1[442368] Wt2[884736] (hole) h1_bf16[51.2e6] sX_bf16[51.2e6]
  //   sums[3 KB in 8 KB slot] zpage[256]
  char* ws = (char*)d_ws;
  unsigned short* Wt1 = (unsigned short*)(ws);
  unsigned short* Wt2 = (unsigned short*)(ws + 442368);
  unsigned short* h1 = (unsigned short*)(ws + 1343488);
  unsigned short* sX = (unsigned short*)(ws + 52543488);
  float* sums1 = (float*)(ws + 103743488);
  float* sums2 = sums1 + 2 * COUT;
  float* sumsd = sums1 + 4 * COUT;
  unsigned short* zpage = (unsigned short*)(ws + 103743488 + 8192);

  float* h2 = (float*)d_out;  // conv2 output -> d_out (fp32)
  // bf16 feats stash: last 25.6 MB of d_out; conv2 clobbers it afterwards
  unsigned short* featsb = (unsigned short*)((char*)d_out + 76800000);

  const int prep_units = (768 + 64) + KOFF * CIN * 128 + KOFF * COUT * 128;
  prep_kernel<<<(prep_units + 255) / 256, 256, 0, stream>>>(
      W1, W2, Wt1, Wt2, sums1, (float*)zpage);

  const int mblocks = (n + 127) / 128;
  convskip_kernel<<<mblocks, 256, 0, stream>>>(feats, Wd, featsb, sX, sumsd, n);

  conv_kernel<CIN, true, false><<<mblocks, 256, 0, stream>>>(
      featsb, nbr1, Wt1, h1, zpage, sums1, n, KOFF);

  const int total8 = n * COUT / 8;
  norm_relu_kernel<<<(total8 + 255) / 256, 256, 0, stream>>>(h1, sums1, g1, b1, n, total8);

  conv_kernel<COUT, true, true><<<mblocks, 256, 0, stream>>>(
      h1, nbr2, Wt2, h2, zpage, sums2, n, KOFF);

  const int total4 = n * COUT / 4;
  final_kernel<<<(total4 + 255) / 256, 256, 0, stream>>>(
      h2, sX, sums2, sumsd, g2, b2, gd, bd, n, total4);
}